// Round 6
// baseline (263.318 us; speedup 1.0000x reference)
//
#include <hip/hip_runtime.h>
#include <hip/hip_bf16.h>

// B=4, T=2048, C=1024 single-head causal attention, fp32 in/out.
// R6: QKV reverted to R3 epilogue (unified qkv, ldc=3072) + standalone
// transpose; rowsum fused into S epilogue via cross-lane reduce + atomicAdd;
// PV split-K with balanced 768-block table + partial-reduce kernel.

typedef short bf16x8 __attribute__((ext_vector_type(8)));
typedef float f32x4  __attribute__((ext_vector_type(4)));

#define T_SEQ 2048
#define EMB   1024
#define NBAT  4

struct alignas(8) bh4 { __hip_bfloat16 a, b, c, d; };

__device__ __forceinline__ bh4 pack4(float x, float y, float z, float w) {
    bh4 o { __float2bfloat16(x), __float2bfloat16(y),
            __float2bfloat16(z), __float2bfloat16(w) };
    return o;
}

// ---------------------------------------------------------------- merged cast
__global__ void cast_all(const float* __restrict__ x,
                         const float* __restrict__ w0,
                         const float* __restrict__ w1,
                         const float* __restrict__ w2,
                         __hip_bfloat16* __restrict__ xb,
                         __hip_bfloat16* __restrict__ wb) {
    const int bid = blockIdx.x;
    if (bid < 8192) {
        int i = bid * 256 + threadIdx.x;
        float4 v = reinterpret_cast<const float4*>(x)[i];
        reinterpret_cast<bh4*>(xb)[i] = pack4(v.x, v.y, v.z, v.w);
    } else {
        int j = bid - 8192;                       // 0..3071
        int sel = j >> 10;
        const float* src = (sel == 0) ? w0 : (sel == 1) ? w1 : w2;
        int i = (j & 1023) * 256 + threadIdx.x;
        float4 v = reinterpret_cast<const float4*>(src)[i];
        reinterpret_cast<bh4*>(wb + (size_t)sel * 1048576)[i] =
            pack4(v.x, v.y, v.z, v.w);
    }
}

// ---------------------------------------------------------------- gemm core
__device__ __forceinline__ void load_lds16(const void* g, void* l) {
    __builtin_amdgcn_global_load_lds(
        (const __attribute__((address_space(1))) void*)g,
        (__attribute__((address_space(3))) void*)l, 16, 0, 0);
}

// C[M,N] = A[M,K]*B[N,K]^T, 128x128 tile, 4 waves, BK=64 (2x 32-k subtiles).
// EPI: 1 = plain bf16 store (QKV).  3 = exp(s/32) masked bf16 + atomic rowsum.
// SWZ: 1 = XCD-slab 1536-block QKV.  2 = compact lower triangle.
template<int EPI, int SWZ>
__global__ __launch_bounds__(256) void gemm_bt(
    const __hip_bfloat16* __restrict__ Abase,
    const __hip_bfloat16* __restrict__ Bbase,
    void* __restrict__ Cbase,
    float* __restrict__ Lbuf,
    int K, int lda, int ldb, int ldc,
    long batchA, long batchB, long batchC)
{
    int ct, rt, bz;
    if (SWZ == 1) {
        const int bid = blockIdx.x;
        const int xcd = bid & 7;
        const int ii  = bid >> 3;            // 0..191
        rt = (xcd << 3) | (ii & 7);          // 0..63
        ct = ii >> 3;                        // 0..23
        bz = 0;
    } else {
        const int bid = blockIdx.x;          // 0..135
        int r = (int)((sqrtf(8.f * bid + 1.f) - 1.f) * 0.5f);
        while ((r + 1) * (r + 2) / 2 <= bid) ++r;
        while (r * (r + 1) / 2 > bid) --r;
        rt = r;
        ct = bid - r * (r + 1) / 2;
        bz = blockIdx.z;
    }

    __shared__ short lsA[2][128 * 32];
    __shared__ short lsB[2][128 * 32];

    const int tid  = threadIdx.x;
    const int wave = tid >> 6;
    const int lane = tid & 63;
    const int wr   = (wave >> 1) * 64;
    const int wc   = (wave &  1) * 64;
    const int srow = wave * 32 + (lane >> 2);
    const int scol = (lane & 3) * 8;
    const int frow = lane & 15;
    const int fk   = (lane >> 4) * 8;

    const short* A = (const short*)Abase + bz * batchA + (long)rt * 128 * lda;
    const short* B = (const short*)Bbase + bz * batchB + (long)ct * 128 * ldb;

    f32x4 acc[4][4] = {};

    for (int k0 = 0; k0 < K; k0 += 64) {
        const short* ga = A + (long)srow * lda + k0 + scol;
        const short* gb = B + (long)srow * ldb + k0 + scol;
        load_lds16(ga,                  &lsA[0][(wave * 32) * 32]);
        load_lds16(ga + 16L * lda,      &lsA[0][(wave * 32 + 16) * 32]);
        load_lds16(ga + 32,             &lsA[1][(wave * 32) * 32]);
        load_lds16(ga + 16L * lda + 32, &lsA[1][(wave * 32 + 16) * 32]);
        load_lds16(gb,                  &lsB[0][(wave * 32) * 32]);
        load_lds16(gb + 16L * ldb,      &lsB[0][(wave * 32 + 16) * 32]);
        load_lds16(gb + 32,             &lsB[1][(wave * 32) * 32]);
        load_lds16(gb + 16L * ldb + 32, &lsB[1][(wave * 32 + 16) * 32]);
        __syncthreads();

        #pragma unroll
        for (int sub = 0; sub < 2; ++sub) {
            bf16x8 af[4], bfr[4];
            #pragma unroll
            for (int m = 0; m < 4; ++m)
                af[m] = *(const bf16x8*)&lsA[sub][(wr + m * 16 + frow) * 32 + fk];
            #pragma unroll
            for (int n = 0; n < 4; ++n)
                bfr[n] = *(const bf16x8*)&lsB[sub][(wc + n * 16 + frow) * 32 + fk];
            #pragma unroll
            for (int m = 0; m < 4; ++m)
                #pragma unroll
                for (int n = 0; n < 4; ++n)
                    acc[m][n] = __builtin_amdgcn_mfma_f32_16x16x32_bf16(
                        af[m], bfr[n], acc[m][n], 0, 0, 0);
        }
        __syncthreads();
    }

    // epilogue: C/D layout col = lane&15, row = (lane>>4)*4 + reg
    const long crow0 = (long)rt * 128 + wr;
    const long ccol0 = (long)ct * 128 + wc;
    const int  orow  = (lane >> 4) * 4;
    const int  ocol  = lane & 15;

    if (EPI == 1) {                           // plain bf16 (QKV -> qkv)
        __hip_bfloat16* C = (__hip_bfloat16*)Cbase;
        #pragma unroll
        for (int m = 0; m < 4; ++m)
            #pragma unroll
            for (int n = 0; n < 4; ++n)
                #pragma unroll
                for (int r = 0; r < 4; ++r)
                    C[(crow0 + m * 16 + orow + r) * ldc + ccol0 + n * 16 + ocol] =
                        __float2bfloat16(acc[m][n][r]);
    } else {                                  // EPI == 3: exp + mask + rowsum
        __hip_bfloat16* C = (__hip_bfloat16*)Cbase + bz * batchC;
        float rsum[4][4];
        #pragma unroll
        for (int m = 0; m < 4; ++m)
            #pragma unroll
            for (int r = 0; r < 4; ++r) rsum[m][r] = 0.f;
        #pragma unroll
        for (int m = 0; m < 4; ++m)
            #pragma unroll
            for (int n = 0; n < 4; ++n)
                #pragma unroll
                for (int r = 0; r < 4; ++r) {
                    const long row = crow0 + m * 16 + orow + r;
                    const long col = ccol0 + n * 16 + ocol;
                    float p = (col <= row) ? __expf(acc[m][n][r] * 0.03125f) : 0.f;
                    C[row * ldc + col] = __float2bfloat16(p);
                    rsum[m][r] += p;
                }
        // reduce across the 16-lane column group, one atomic per row
        #pragma unroll
        for (int m = 0; m < 4; ++m)
            #pragma unroll
            for (int r = 0; r < 4; ++r) {
                float v = rsum[m][r];
                v += __shfl_xor(v, 1);
                v += __shfl_xor(v, 2);
                v += __shfl_xor(v, 4);
                v += __shfl_xor(v, 8);
                if ((lane & 15) == 0)
                    atomicAdd(&Lbuf[bz * T_SEQ + crow0 + m * 16 + orow + r], v);
            }
    }
}

// ---------------------------------------------------------------- V transpose
// V at qkv col offset 2048, row stride 3072 -> vT [B][EMB][T] bf16.
__global__ void transpose_v(const __hip_bfloat16* __restrict__ QKV,
                            __hip_bfloat16* __restrict__ vT) {
    __shared__ __hip_bfloat16 tile[64][65];
    const int b  = blockIdx.z;
    const int t0 = blockIdx.x * 64;
    const int d0 = blockIdx.y * 64;
    const int tid = threadIdx.x;           // 256
    const int c  = tid & 63;
    const int r4 = tid >> 6;
    #pragma unroll
    for (int i = 0; i < 16; ++i) {
        int row = r4 + i * 4;
        tile[row][c] = QKV[(size_t)(b * T_SEQ + t0 + row) * 3072 + 2048 + d0 + c];
    }
    __syncthreads();
    #pragma unroll
    for (int i = 0; i < 16; ++i) {
        int drow = r4 + i * 4;
        vT[((size_t)b * EMB + d0 + drow) * T_SEQ + t0 + c] = tile[c][drow];
    }
}

// ---------------------------------------------------------------- PV split-K
// 768 blocks: y in [0,24) decodes (rt, kstart, ktiles) from a size-balanced
// table (CU triples sum to ~17 K-tiles). rt<8: direct scaled to d_out.
// rt>=8: two parts write unscaled fp32 partials to tmp0/tmp1.
__device__ const int PV_RT[24] = {15,15,14,14,13,13,12,12, 7,6,11,11,10,10,9,5, 0,1,2,3,8,9,8,4};
__device__ const int PV_KS[24] = { 0, 8, 0, 8, 0, 7, 0, 7, 0,0, 0, 6, 0, 6,0,0, 0,0,0,0,5,5,0,0};
__device__ const int PV_KT[24] = { 8, 8, 8, 7, 7, 7, 7, 6, 8,7, 6, 6, 6, 5,5,6, 1,2,3,4,4,5,5,5};

__global__ __launch_bounds__(256) void pv_split(
    const __hip_bfloat16* __restrict__ P,
    const __hip_bfloat16* __restrict__ Vt,
    float* __restrict__ out,
    float* __restrict__ tmp0,
    float* __restrict__ tmp1,
    const float* __restrict__ Lbuf)
{
    const int ct = blockIdx.x;               // 0..7
    const int y  = blockIdx.y;               // 0..23
    const int bz = blockIdx.z;
    const int rt = PV_RT[y];
    const int k0s = PV_KS[y] * 128;
    const int k0e = k0s + PV_KT[y] * 128;

    __shared__ short lsA[2][128 * 32];
    __shared__ short lsB[2][128 * 32];

    const int tid  = threadIdx.x;
    const int wave = tid >> 6;
    const int lane = tid & 63;
    const int wr   = (wave >> 1) * 64;
    const int wc   = (wave &  1) * 64;
    const int srow = wave * 32 + (lane >> 2);
    const int scol = (lane & 3) * 8;
    const int frow = lane & 15;
    const int fk   = (lane >> 4) * 8;

    const short* A = (const short*)P  + (long)bz * 4194304 + (long)rt * 128 * 2048;
    const short* B = (const short*)Vt + (long)bz * 2097152 + (long)ct * 128 * 2048;

    f32x4 acc[4][4] = {};

    for (int k0 = k0s; k0 < k0e; k0 += 64) {
        const short* ga = A + (long)srow * 2048 + k0 + scol;
        const short* gb = B + (long)srow * 2048 + k0 + scol;
        load_lds16(ga,                   &lsA[0][(wave * 32) * 32]);
        load_lds16(ga + 16L * 2048,      &lsA[0][(wave * 32 + 16) * 32]);
        load_lds16(ga + 32,              &lsA[1][(wave * 32) * 32]);
        load_lds16(ga + 16L * 2048 + 32, &lsA[1][(wave * 32 + 16) * 32]);
        load_lds16(gb,                   &lsB[0][(wave * 32) * 32]);
        load_lds16(gb + 16L * 2048,      &lsB[0][(wave * 32 + 16) * 32]);
        load_lds16(gb + 32,              &lsB[1][(wave * 32) * 32]);
        load_lds16(gb + 16L * 2048 + 32, &lsB[1][(wave * 32 + 16) * 32]);
        __syncthreads();

        #pragma unroll
        for (int sub = 0; sub < 2; ++sub) {
            bf16x8 af[4], bfr[4];
            #pragma unroll
            for (int m = 0; m < 4; ++m)
                af[m] = *(const bf16x8*)&lsA[sub][(wr + m * 16 + frow) * 32 + fk];
            #pragma unroll
            for (int n = 0; n < 4; ++n)
                bfr[n] = *(const bf16x8*)&lsB[sub][(wc + n * 16 + frow) * 32 + fk];
            #pragma unroll
            for (int m = 0; m < 4; ++m)
                #pragma unroll
                for (int n = 0; n < 4; ++n)
                    acc[m][n] = __builtin_amdgcn_mfma_f32_16x16x32_bf16(
                        af[m], bfr[n], acc[m][n], 0, 0, 0);
        }
        __syncthreads();
    }

    const int orow = (lane >> 4) * 4;
    const int ocol = lane & 15;

    if (rt < 8) {                            // direct, scaled
        #pragma unroll
        for (int m = 0; m < 4; ++m)
            #pragma unroll
            for (int r = 0; r < 4; ++r) {
                const long row = (long)rt * 128 + wr + m * 16 + orow + r;
                const float s = 1.f / Lbuf[bz * T_SEQ + row];
                #pragma unroll
                for (int n = 0; n < 4; ++n)
                    out[(long)bz * 2097152 + row * 1024 +
                        ct * 128 + wc + n * 16 + ocol] = acc[m][n][r] * s;
            }
    } else {                                 // unscaled partial
        float* T = (k0s == 0) ? tmp0 : tmp1;
        #pragma unroll
        for (int m = 0; m < 4; ++m)
            #pragma unroll
            for (int r = 0; r < 4; ++r) {
                const long lrow = (long)(rt - 8) * 128 + wr + m * 16 + orow + r;
                #pragma unroll
                for (int n = 0; n < 4; ++n)
                    T[((long)bz * 1024 + lrow) * 1024 +
                      ct * 128 + wc + n * 16 + ocol] = acc[m][n][r];
            }
    }
}

// ---------------------------------------------------------------- PV reduce
// rows 1024..2047 per batch: out = (tmp0 + tmp1) * invl
__global__ void pv_reduce(const float* __restrict__ t0,
                          const float* __restrict__ t1,
                          const float* __restrict__ Lbuf,
                          float* __restrict__ out) {
    const int row = blockIdx.x;              // 0..4095
    const int b   = row >> 10;
    const int r   = row & 1023;
    const int c   = threadIdx.x * 4;
    const float s = 1.f / Lbuf[b * T_SEQ + 1024 + r];
    float4 a = *(const float4*)&t0[(size_t)row * 1024 + c];
    float4 d = *(const float4*)&t1[(size_t)row * 1024 + c];
    float4 o = make_float4((a.x + d.x) * s, (a.y + d.y) * s,
                           (a.z + d.z) * s, (a.w + d.w) * s);
    *(float4*)&out[((size_t)b * 2097152) + (size_t)(1024 + r) * 1024 + c] = o;
}

// ---------------------------------------------------------------- launch
extern "C" void kernel_launch(void* const* d_in, const int* in_sizes, int n_in,
                              void* d_out, int out_size, void* d_ws, size_t ws_size,
                              hipStream_t stream) {
    const float* x  = (const float*)d_in[0];
    const float* Wq = (const float*)d_in[1];
    const float* Wk = (const float*)d_in[2];
    const float* Wv = (const float*)d_in[3];

    char* ws = (char*)d_ws;
    // workspace (bytes):
    //   xb   @ 0         : 16,777,216   (dead after QKV; tmp0 aliases)
    //   wb   @ 16777216  :  6,291,456
    //   qkv  @ 23068672  : 50,331,648   (Q|K|V cols; Q region dead after S;
    //                                    tmp1 aliases first 16.8 MB)
    //   vT   @ 73400320  : 16,777,216
    //   P    @ 90177536  : 33,554,432
    //   l    @ 123731968 :     32,768
    // total 123,764,736
    __hip_bfloat16* xb   = (__hip_bfloat16*)(ws);
    __hip_bfloat16* wb   = (__hip_bfloat16*)(ws + 16777216);
    __hip_bfloat16* qkv  = (__hip_bfloat16*)(ws + 23068672);
    __hip_bfloat16* vT   = (__hip_bfloat16*)(ws + 73400320);
    __hip_bfloat16* P    = (__hip_bfloat16*)(ws + 90177536);
    float*          Lbuf = (float*)        (ws + 123731968);
    float*          tmp0 = (float*)        (ws);              // aliases xb
    float*          tmp1 = (float*)        (ws + 23068672);   // aliases Q rows

    // 0) zero the rowsum accumulator
    hipMemsetAsync(Lbuf, 0, 32768, stream);

    // 1) casts
    cast_all<<<dim3(11264), 256, 0, stream>>>(x, Wq, Wk, Wv, xb, wb);

    // 2) fused QKV -> qkv [8192][3072], XCD slab swizzle (R3 config)
    gemm_bt<1, 1><<<dim3(1536), 256, 0, stream>>>(
        xb, wb, qkv, nullptr,
        /*K*/1024, /*lda*/1024, /*ldb*/1024, /*ldc*/3072,
        0L, 0L, 0L);

    // 3) V^T per batch
    transpose_v<<<dim3(32, 16, 4), 256, 0, stream>>>(qkv, vT);

    // 4) P = exp(mask(QK^T)/32) bf16 + atomic rowsums, triangle launch
    gemm_bt<3, 2><<<dim3(136, 1, 4), 256, 0, stream>>>(
        qkv, qkv + 1024, P, Lbuf,
        /*K*/1024, /*lda*/3072, /*ldb*/3072, /*ldc*/2048,
        /*bA*/6291456L, /*bB*/6291456L, /*bC*/4194304L);

    // 5) O = (P @ V) * invl ; balanced split-K, 768 blocks
    pv_split<<<dim3(8, 24, 4), 256, 0, stream>>>(
        P, vT, (float*)d_out, tmp0, tmp1, Lbuf);

    // 6) combine split partials for rows 1024+
    pv_reduce<<<dim3(4096), 256, 0, stream>>>(tmp0, tmp1, Lbuf, (float*)d_out);
}

// Round 7
// 262.966 us; speedup vs baseline: 1.0013x; 1.0013x over previous
//
#include <hip/hip_runtime.h>
#include <hip/hip_bf16.h>

// B=4, T=2048, C=1024 single-head causal attention, fp32 in/out.
// R7: PV split-K rebuilt lean (uniform parts, single plain-store epilogue,
// VGPR-light -> 3 blocks/CU co-residency) + pv_finish scale/combine;
// Lbuf zeroing folded into cast_all. QKV/transpose/S as R6.

typedef short bf16x8 __attribute__((ext_vector_type(8)));
typedef float f32x4  __attribute__((ext_vector_type(4)));

#define T_SEQ 2048
#define EMB   1024
#define NBAT  4

struct alignas(8) bh4 { __hip_bfloat16 a, b, c, d; };

__device__ __forceinline__ bh4 pack4(float x, float y, float z, float w) {
    bh4 o { __float2bfloat16(x), __float2bfloat16(y),
            __float2bfloat16(z), __float2bfloat16(w) };
    return o;
}

// ---------------------------------------------------------------- merged cast
// bid < 8192: x. 8192..11263: Wq|Wk|Wv. >= 11264: zero Lbuf (8192 floats).
__global__ void cast_all(const float* __restrict__ x,
                         const float* __restrict__ w0,
                         const float* __restrict__ w1,
                         const float* __restrict__ w2,
                         __hip_bfloat16* __restrict__ xb,
                         __hip_bfloat16* __restrict__ wb,
                         float* __restrict__ Lbuf) {
    const int bid = blockIdx.x;
    if (bid < 8192) {
        int i = bid * 256 + threadIdx.x;
        float4 v = reinterpret_cast<const float4*>(x)[i];
        reinterpret_cast<bh4*>(xb)[i] = pack4(v.x, v.y, v.z, v.w);
    } else if (bid < 11264) {
        int j = bid - 8192;                       // 0..3071
        int sel = j >> 10;
        const float* src = (sel == 0) ? w0 : (sel == 1) ? w1 : w2;
        int i = (j & 1023) * 256 + threadIdx.x;
        float4 v = reinterpret_cast<const float4*>(src)[i];
        reinterpret_cast<bh4*>(wb + (size_t)sel * 1048576)[i] =
            pack4(v.x, v.y, v.z, v.w);
    } else {
        Lbuf[(bid - 11264) * 256 + threadIdx.x] = 0.f;
    }
}

// ---------------------------------------------------------------- gemm core
__device__ __forceinline__ void load_lds16(const void* g, void* l) {
    __builtin_amdgcn_global_load_lds(
        (const __attribute__((address_space(1))) void*)g,
        (__attribute__((address_space(3))) void*)l, 16, 0, 0);
}

// C[M,N] = A[M,K]*B[N,K]^T, 128x128 tile, 4 waves, BK=64 (2x 32-k subtiles).
// EPI: 1 = plain bf16 store (QKV).  3 = exp(s/32) masked bf16 + atomic rowsum.
// SWZ: 1 = XCD-slab 1536-block QKV.  2 = compact lower triangle.
template<int EPI, int SWZ>
__global__ __launch_bounds__(256) void gemm_bt(
    const __hip_bfloat16* __restrict__ Abase,
    const __hip_bfloat16* __restrict__ Bbase,
    void* __restrict__ Cbase,
    float* __restrict__ Lbuf,
    int K, int lda, int ldb, int ldc,
    long batchA, long batchB, long batchC)
{
    int ct, rt, bz;
    if (SWZ == 1) {
        const int bid = blockIdx.x;
        const int xcd = bid & 7;
        const int ii  = bid >> 3;            // 0..191
        rt = (xcd << 3) | (ii & 7);          // 0..63
        ct = ii >> 3;                        // 0..23
        bz = 0;
    } else {
        const int bid = blockIdx.x;          // 0..135
        int r = (int)((sqrtf(8.f * bid + 1.f) - 1.f) * 0.5f);
        while ((r + 1) * (r + 2) / 2 <= bid) ++r;
        while (r * (r + 1) / 2 > bid) --r;
        rt = r;
        ct = bid - r * (r + 1) / 2;
        bz = blockIdx.z;
    }

    __shared__ short lsA[2][128 * 32];
    __shared__ short lsB[2][128 * 32];

    const int tid  = threadIdx.x;
    const int wave = tid >> 6;
    const int lane = tid & 63;
    const int wr   = (wave >> 1) * 64;
    const int wc   = (wave &  1) * 64;
    const int srow = wave * 32 + (lane >> 2);
    const int scol = (lane & 3) * 8;
    const int frow = lane & 15;
    const int fk   = (lane >> 4) * 8;

    const short* A = (const short*)Abase + bz * batchA + (long)rt * 128 * lda;
    const short* B = (const short*)Bbase + bz * batchB + (long)ct * 128 * ldb;

    f32x4 acc[4][4] = {};

    for (int k0 = 0; k0 < K; k0 += 64) {
        const short* ga = A + (long)srow * lda + k0 + scol;
        const short* gb = B + (long)srow * ldb + k0 + scol;
        load_lds16(ga,                  &lsA[0][(wave * 32) * 32]);
        load_lds16(ga + 16L * lda,      &lsA[0][(wave * 32 + 16) * 32]);
        load_lds16(ga + 32,             &lsA[1][(wave * 32) * 32]);
        load_lds16(ga + 16L * lda + 32, &lsA[1][(wave * 32 + 16) * 32]);
        load_lds16(gb,                  &lsB[0][(wave * 32) * 32]);
        load_lds16(gb + 16L * ldb,      &lsB[0][(wave * 32 + 16) * 32]);
        load_lds16(gb + 32,             &lsB[1][(wave * 32) * 32]);
        load_lds16(gb + 16L * ldb + 32, &lsB[1][(wave * 32 + 16) * 32]);
        __syncthreads();

        #pragma unroll
        for (int sub = 0; sub < 2; ++sub) {
            bf16x8 af[4], bfr[4];
            #pragma unroll
            for (int m = 0; m < 4; ++m)
                af[m] = *(const bf16x8*)&lsA[sub][(wr + m * 16 + frow) * 32 + fk];
            #pragma unroll
            for (int n = 0; n < 4; ++n)
                bfr[n] = *(const bf16x8*)&lsB[sub][(wc + n * 16 + frow) * 32 + fk];
            #pragma unroll
            for (int m = 0; m < 4; ++m)
                #pragma unroll
                for (int n = 0; n < 4; ++n)
                    acc[m][n] = __builtin_amdgcn_mfma_f32_16x16x32_bf16(
                        af[m], bfr[n], acc[m][n], 0, 0, 0);
        }
        __syncthreads();
    }

    // epilogue: C/D layout col = lane&15, row = (lane>>4)*4 + reg
    const long crow0 = (long)rt * 128 + wr;
    const long ccol0 = (long)ct * 128 + wc;
    const int  orow  = (lane >> 4) * 4;
    const int  ocol  = lane & 15;

    if (EPI == 1) {                           // plain bf16 (QKV -> qkv)
        __hip_bfloat16* C = (__hip_bfloat16*)Cbase;
        #pragma unroll
        for (int m = 0; m < 4; ++m)
            #pragma unroll
            for (int n = 0; n < 4; ++n)
                #pragma unroll
                for (int r = 0; r < 4; ++r)
                    C[(crow0 + m * 16 + orow + r) * ldc + ccol0 + n * 16 + ocol] =
                        __float2bfloat16(acc[m][n][r]);
    } else {                                  // EPI == 3: exp + mask + rowsum
        __hip_bfloat16* C = (__hip_bfloat16*)Cbase + bz * batchC;
        float rsum[4][4];
        #pragma unroll
        for (int m = 0; m < 4; ++m)
            #pragma unroll
            for (int r = 0; r < 4; ++r) rsum[m][r] = 0.f;
        #pragma unroll
        for (int m = 0; m < 4; ++m)
            #pragma unroll
            for (int n = 0; n < 4; ++n)
                #pragma unroll
                for (int r = 0; r < 4; ++r) {
                    const long row = crow0 + m * 16 + orow + r;
                    const long col = ccol0 + n * 16 + ocol;
                    float p = (col <= row) ? __expf(acc[m][n][r] * 0.03125f) : 0.f;
                    C[row * ldc + col] = __float2bfloat16(p);
                    rsum[m][r] += p;
                }
        #pragma unroll
        for (int m = 0; m < 4; ++m)
            #pragma unroll
            for (int r = 0; r < 4; ++r) {
                float v = rsum[m][r];
                v += __shfl_xor(v, 1);
                v += __shfl_xor(v, 2);
                v += __shfl_xor(v, 4);
                v += __shfl_xor(v, 8);
                if ((lane & 15) == 0)
                    atomicAdd(&Lbuf[bz * T_SEQ + crow0 + m * 16 + orow + r], v);
            }
    }
}

// ---------------------------------------------------------------- V transpose
__global__ void transpose_v(const __hip_bfloat16* __restrict__ QKV,
                            __hip_bfloat16* __restrict__ vT) {
    __shared__ __hip_bfloat16 tile[64][65];
    const int b  = blockIdx.z;
    const int t0 = blockIdx.x * 64;
    const int d0 = blockIdx.y * 64;
    const int tid = threadIdx.x;           // 256
    const int c  = tid & 63;
    const int r4 = tid >> 6;
    #pragma unroll
    for (int i = 0; i < 16; ++i) {
        int row = r4 + i * 4;
        tile[row][c] = QKV[(size_t)(b * T_SEQ + t0 + row) * 3072 + 2048 + d0 + c];
    }
    __syncthreads();
    #pragma unroll
    for (int i = 0; i < 16; ++i) {
        int drow = r4 + i * 4;
        vT[((size_t)b * EMB + d0 + drow) * T_SEQ + t0 + c] = tile[c][drow];
    }
}

// ---------------------------------------------------------------- PV split-K
// y<8: rt=y, full K=(rt+1)*128, -> d_out (unscaled).
// y>=8: j=y-8, rt=8+(j>>1); part0 (j even): K tiles [0,8) -> d_out;
//       part1 (j odd): tiles [8, rt+1) -> tmp1 rows (rt-8)*128.
// Single plain fp32-store epilogue; scaling deferred to pv_finish.
__global__ __launch_bounds__(256) void pv_split(
    const __hip_bfloat16* __restrict__ P,
    const __hip_bfloat16* __restrict__ Vt,
    float* __restrict__ out,
    float* __restrict__ tmp1)
{
    const int ct = blockIdx.x;               // 0..7
    const int y  = blockIdx.y;               // 0..23
    const int bz = blockIdx.z;

    int rt, k0s, k0e;
    float* dst;
    if (y < 8) {
        rt = y; k0s = 0; k0e = (rt + 1) * 128;
        dst = out + (long)bz * 2097152 + (long)rt * 128 * 1024;
    } else {
        const int j = y - 8;
        rt = 8 + (j >> 1);
        if (j & 1) {
            k0s = 1024; k0e = (rt + 1) * 128;
            dst = tmp1 + ((long)bz * 1024 + (long)(rt - 8) * 128) * 1024;
        } else {
            k0s = 0; k0e = 1024;
            dst = out + (long)bz * 2097152 + (long)rt * 128 * 1024;
        }
    }

    __shared__ short lsA[2][128 * 32];
    __shared__ short lsB[2][128 * 32];

    const int tid  = threadIdx.x;
    const int wave = tid >> 6;
    const int lane = tid & 63;
    const int wr   = (wave >> 1) * 64;
    const int wc   = (wave &  1) * 64;
    const int srow = wave * 32 + (lane >> 2);
    const int scol = (lane & 3) * 8;
    const int frow = lane & 15;
    const int fk   = (lane >> 4) * 8;

    const short* A = (const short*)P  + (long)bz * 4194304 + (long)rt * 128 * 2048;
    const short* B = (const short*)Vt + (long)bz * 2097152 + (long)ct * 128 * 2048;

    f32x4 acc[4][4] = {};

    for (int k0 = k0s; k0 < k0e; k0 += 64) {
        const short* ga = A + (long)srow * 2048 + k0 + scol;
        const short* gb = B + (long)srow * 2048 + k0 + scol;
        load_lds16(ga,                   &lsA[0][(wave * 32) * 32]);
        load_lds16(ga + 16L * 2048,      &lsA[0][(wave * 32 + 16) * 32]);
        load_lds16(ga + 32,              &lsA[1][(wave * 32) * 32]);
        load_lds16(ga + 16L * 2048 + 32, &lsA[1][(wave * 32 + 16) * 32]);
        load_lds16(gb,                   &lsB[0][(wave * 32) * 32]);
        load_lds16(gb + 16L * 2048,      &lsB[0][(wave * 32 + 16) * 32]);
        load_lds16(gb + 32,              &lsB[1][(wave * 32) * 32]);
        load_lds16(gb + 16L * 2048 + 32, &lsB[1][(wave * 32 + 16) * 32]);
        __syncthreads();

        #pragma unroll
        for (int sub = 0; sub < 2; ++sub) {
            bf16x8 af[4], bfr[4];
            #pragma unroll
            for (int m = 0; m < 4; ++m)
                af[m] = *(const bf16x8*)&lsA[sub][(wr + m * 16 + frow) * 32 + fk];
            #pragma unroll
            for (int n = 0; n < 4; ++n)
                bfr[n] = *(const bf16x8*)&lsB[sub][(wc + n * 16 + frow) * 32 + fk];
            #pragma unroll
            for (int m = 0; m < 4; ++m)
                #pragma unroll
                for (int n = 0; n < 4; ++n)
                    acc[m][n] = __builtin_amdgcn_mfma_f32_16x16x32_bf16(
                        af[m], bfr[n], acc[m][n], 0, 0, 0);
        }
        __syncthreads();
    }

    const int orow = (lane >> 4) * 4;
    const int ocol = lane & 15;
    #pragma unroll
    for (int m = 0; m < 4; ++m)
        #pragma unroll
        for (int r = 0; r < 4; ++r) {
            const long lrow = wr + m * 16 + orow + r;
            #pragma unroll
            for (int n = 0; n < 4; ++n)
                dst[lrow * 1024 + ct * 128 + wc + n * 16 + ocol] = acc[m][n][r];
        }
}

// ---------------------------------------------------------------- PV finish
// rows < 1024 (per batch): out *= 1/l.  rows >= 1024: out = (out+tmp1)/l.
__global__ void pv_finish(float* __restrict__ out,
                          const float* __restrict__ tmp1,
                          const float* __restrict__ Lbuf) {
    const int g = blockIdx.x;                // 0..8191
    const int b = g >> 11;
    const int r = g & 2047;
    const int c = threadIdx.x * 4;
    const float s = 1.f / Lbuf[b * T_SEQ + r];
    float* po = out + (long)b * 2097152 + (long)r * 1024 + c;
    float4 o = *(const float4*)po;
    if (r >= 1024) {
        float4 t = *(const float4*)&tmp1[((long)b * 1024 + (r - 1024)) * 1024 + c];
        o.x += t.x; o.y += t.y; o.z += t.z; o.w += t.w;
    }
    o.x *= s; o.y *= s; o.z *= s; o.w *= s;
    *(float4*)po = o;
}

// ---------------------------------------------------------------- launch
extern "C" void kernel_launch(void* const* d_in, const int* in_sizes, int n_in,
                              void* d_out, int out_size, void* d_ws, size_t ws_size,
                              hipStream_t stream) {
    const float* x  = (const float*)d_in[0];
    const float* Wq = (const float*)d_in[1];
    const float* Wk = (const float*)d_in[2];
    const float* Wv = (const float*)d_in[3];

    char* ws = (char*)d_ws;
    // workspace (bytes):
    //   xb   @ 0         : 16,777,216   (dead after QKV; tmp1 aliases)
    //   wb   @ 16777216  :  6,291,456
    //   qkv  @ 23068672  : 50,331,648   (Q|K|V cols)
    //   vT   @ 73400320  : 16,777,216
    //   P    @ 90177536  : 33,554,432
    //   l    @ 123731968 :     32,768
    __hip_bfloat16* xb   = (__hip_bfloat16*)(ws);
    __hip_bfloat16* wb   = (__hip_bfloat16*)(ws + 16777216);
    __hip_bfloat16* qkv  = (__hip_bfloat16*)(ws + 23068672);
    __hip_bfloat16* vT   = (__hip_bfloat16*)(ws + 73400320);
    __hip_bfloat16* P    = (__hip_bfloat16*)(ws + 90177536);
    float*          Lbuf = (float*)        (ws + 123731968);
    float*          tmp1 = (float*)        (ws);              // aliases xb

    // 1) casts + Lbuf zero
    cast_all<<<dim3(11296), 256, 0, stream>>>(x, Wq, Wk, Wv, xb, wb, Lbuf);

    // 2) fused QKV -> qkv [8192][3072], XCD slab swizzle
    gemm_bt<1, 1><<<dim3(1536), 256, 0, stream>>>(
        xb, wb, qkv, nullptr,
        /*K*/1024, /*lda*/1024, /*ldb*/1024, /*ldc*/3072,
        0L, 0L, 0L);

    // 3) V^T per batch
    transpose_v<<<dim3(32, 16, 4), 256, 0, stream>>>(qkv, vT);

    // 4) P = exp(mask(QK^T)/32) bf16 + atomic rowsums, triangle launch
    gemm_bt<3, 2><<<dim3(136, 1, 4), 256, 0, stream>>>(
        qkv, qkv + 1024, P, Lbuf,
        /*K*/1024, /*lda*/3072, /*ldb*/3072, /*ldc*/2048,
        /*bA*/6291456L, /*bB*/6291456L, /*bC*/4194304L);

    // 5) O_unscaled = P @ V ; uniform split-K, 768 lean blocks
    pv_split<<<dim3(8, 24, 4), 256, 0, stream>>>(
        P, vT, (float*)d_out, tmp1);

    // 6) combine + scale
    pv_finish<<<dim3(8192), 256, 0, stream>>>((float*)d_out, tmp1, Lbuf);
}

// Round 8
// 247.994 us; speedup vs baseline: 1.0618x; 1.0604x over previous
//
#include <hip/hip_runtime.h>
#include <hip/hip_bf16.h>

// B=4, T=2048, C=1024 single-head causal attention, fp32 in/out.
// R8: XCD-group decode for S and PV (per-XCD L2-resident working sets,
// same medicine as the QKV slab swizzle); direct PV rows scaled in-epilogue;
// pv_finish shrunk to split rows only.

typedef short bf16x8 __attribute__((ext_vector_type(8)));
typedef float f32x4  __attribute__((ext_vector_type(4)));

#define T_SEQ 2048
#define EMB   1024
#define NBAT  4

struct alignas(8) bh4 { __hip_bfloat16 a, b, c, d; };

__device__ __forceinline__ bh4 pack4(float x, float y, float z, float w) {
    bh4 o { __float2bfloat16(x), __float2bfloat16(y),
            __float2bfloat16(z), __float2bfloat16(w) };
    return o;
}

// ---------------------------------------------------------------- merged cast
__global__ void cast_all(const float* __restrict__ x,
                         const float* __restrict__ w0,
                         const float* __restrict__ w1,
                         const float* __restrict__ w2,
                         __hip_bfloat16* __restrict__ xb,
                         __hip_bfloat16* __restrict__ wb,
                         float* __restrict__ Lbuf) {
    const int bid = blockIdx.x;
    if (bid < 8192) {
        int i = bid * 256 + threadIdx.x;
        float4 v = reinterpret_cast<const float4*>(x)[i];
        reinterpret_cast<bh4*>(xb)[i] = pack4(v.x, v.y, v.z, v.w);
    } else if (bid < 11264) {
        int j = bid - 8192;                       // 0..3071
        int sel = j >> 10;
        const float* src = (sel == 0) ? w0 : (sel == 1) ? w1 : w2;
        int i = (j & 1023) * 256 + threadIdx.x;
        float4 v = reinterpret_cast<const float4*>(src)[i];
        reinterpret_cast<bh4*>(wb + (size_t)sel * 1048576)[i] =
            pack4(v.x, v.y, v.z, v.w);
    } else {
        Lbuf[(bid - 11264) * 256 + threadIdx.x] = 0.f;
    }
}

// ---------------------------------------------------------------- gemm core
__device__ __forceinline__ void load_lds16(const void* g, void* l) {
    __builtin_amdgcn_global_load_lds(
        (const __attribute__((address_space(1))) void*)g,
        (__attribute__((address_space(3))) void*)l, 16, 0, 0);
}

// S-triangle slab tables: half0 rts {12..15, 0..3}, half1 {8..11, 4..7};
// counts are rt+1 (68 tiles per (batch, half) group).
__device__ __constant__ int S_RT0[8] = {12, 13, 14, 15, 0, 1, 2, 3};
__device__ __constant__ int S_RT1[8] = {8, 9, 10, 11, 4, 5, 6, 7};

// C[M,N] = A[M,K]*B[N,K]^T, 128x128 tile, 4 waves, BK=64 (2x 32-k subtiles).
// EPI: 1 = plain bf16 store (QKV).  3 = exp(s/32) masked bf16 + atomic rowsum.
// SWZ: 1 = XCD-slab 1536-block QKV.  3 = XCD-grouped triangle (544 blocks).
template<int EPI, int SWZ>
__global__ __launch_bounds__(256) void gemm_bt(
    const __hip_bfloat16* __restrict__ Abase,
    const __hip_bfloat16* __restrict__ Bbase,
    void* __restrict__ Cbase,
    float* __restrict__ Lbuf,
    int K, int lda, int ldb, int ldc,
    long batchA, long batchB, long batchC)
{
    int ct, rt, bz;
    if (SWZ == 1) {
        const int bid = blockIdx.x;
        const int xcd = bid & 7;
        const int ii  = bid >> 3;            // 0..191
        rt = (xcd << 3) | (ii & 7);          // 0..63
        ct = ii >> 3;                        // 0..23
        bz = 0;
    } else {                                  // SWZ == 3: XCD-grouped triangle
        const int bid = blockIdx.x;           // 0..543
        const int xcd = bid & 7;
        bz = xcd >> 1;
        const int* rts = (xcd & 1) ? S_RT1 : S_RT0;
        int idx = bid >> 3;                   // 0..67
        int seg = 0;
        while (idx >= rts[seg] + 1) { idx -= rts[seg] + 1; ++seg; }
        rt = rts[seg];
        ct = idx;
    }

    __shared__ short lsA[2][128 * 32];
    __shared__ short lsB[2][128 * 32];

    const int tid  = threadIdx.x;
    const int wave = tid >> 6;
    const int lane = tid & 63;
    const int wr   = (wave >> 1) * 64;
    const int wc   = (wave &  1) * 64;
    const int srow = wave * 32 + (lane >> 2);
    const int scol = (lane & 3) * 8;
    const int frow = lane & 15;
    const int fk   = (lane >> 4) * 8;

    const short* A = (const short*)Abase + bz * batchA + (long)rt * 128 * lda;
    const short* B = (const short*)Bbase + bz * batchB + (long)ct * 128 * ldb;

    f32x4 acc[4][4] = {};

    for (int k0 = 0; k0 < K; k0 += 64) {
        const short* ga = A + (long)srow * lda + k0 + scol;
        const short* gb = B + (long)srow * ldb + k0 + scol;
        load_lds16(ga,                  &lsA[0][(wave * 32) * 32]);
        load_lds16(ga + 16L * lda,      &lsA[0][(wave * 32 + 16) * 32]);
        load_lds16(ga + 32,             &lsA[1][(wave * 32) * 32]);
        load_lds16(ga + 16L * lda + 32, &lsA[1][(wave * 32 + 16) * 32]);
        load_lds16(gb,                  &lsB[0][(wave * 32) * 32]);
        load_lds16(gb + 16L * ldb,      &lsB[0][(wave * 32 + 16) * 32]);
        load_lds16(gb + 32,             &lsB[1][(wave * 32) * 32]);
        load_lds16(gb + 16L * ldb + 32, &lsB[1][(wave * 32 + 16) * 32]);
        __syncthreads();

        #pragma unroll
        for (int sub = 0; sub < 2; ++sub) {
            bf16x8 af[4], bfr[4];
            #pragma unroll
            for (int m = 0; m < 4; ++m)
                af[m] = *(const bf16x8*)&lsA[sub][(wr + m * 16 + frow) * 32 + fk];
            #pragma unroll
            for (int n = 0; n < 4; ++n)
                bfr[n] = *(const bf16x8*)&lsB[sub][(wc + n * 16 + frow) * 32 + fk];
            #pragma unroll
            for (int m = 0; m < 4; ++m)
                #pragma unroll
                for (int n = 0; n < 4; ++n)
                    acc[m][n] = __builtin_amdgcn_mfma_f32_16x16x32_bf16(
                        af[m], bfr[n], acc[m][n], 0, 0, 0);
        }
        __syncthreads();
    }

    // epilogue: C/D layout col = lane&15, row = (lane>>4)*4 + reg
    const long crow0 = (long)rt * 128 + wr;
    const long ccol0 = (long)ct * 128 + wc;
    const int  orow  = (lane >> 4) * 4;
    const int  ocol  = lane & 15;

    if (EPI == 1) {                           // plain bf16 (QKV -> qkv)
        __hip_bfloat16* C = (__hip_bfloat16*)Cbase;
        #pragma unroll
        for (int m = 0; m < 4; ++m)
            #pragma unroll
            for (int n = 0; n < 4; ++n)
                #pragma unroll
                for (int r = 0; r < 4; ++r)
                    C[(crow0 + m * 16 + orow + r) * ldc + ccol0 + n * 16 + ocol] =
                        __float2bfloat16(acc[m][n][r]);
    } else {                                  // EPI == 3: exp + mask + rowsum
        __hip_bfloat16* C = (__hip_bfloat16*)Cbase + bz * batchC;
        float rsum[4][4];
        #pragma unroll
        for (int m = 0; m < 4; ++m)
            #pragma unroll
            for (int r = 0; r < 4; ++r) rsum[m][r] = 0.f;
        #pragma unroll
        for (int m = 0; m < 4; ++m)
            #pragma unroll
            for (int n = 0; n < 4; ++n)
                #pragma unroll
                for (int r = 0; r < 4; ++r) {
                    const long row = crow0 + m * 16 + orow + r;
                    const long col = ccol0 + n * 16 + ocol;
                    float p = (col <= row) ? __expf(acc[m][n][r] * 0.03125f) : 0.f;
                    C[row * ldc + col] = __float2bfloat16(p);
                    rsum[m][r] += p;
                }
        #pragma unroll
        for (int m = 0; m < 4; ++m)
            #pragma unroll
            for (int r = 0; r < 4; ++r) {
                float v = rsum[m][r];
                v += __shfl_xor(v, 1);
                v += __shfl_xor(v, 2);
                v += __shfl_xor(v, 4);
                v += __shfl_xor(v, 8);
                if ((lane & 15) == 0)
                    atomicAdd(&Lbuf[bz * T_SEQ + crow0 + m * 16 + orow + r], v);
            }
    }
}

// ---------------------------------------------------------------- V transpose
__global__ void transpose_v(const __hip_bfloat16* __restrict__ QKV,
                            __hip_bfloat16* __restrict__ vT) {
    __shared__ __hip_bfloat16 tile[64][65];
    const int b  = blockIdx.z;
    const int t0 = blockIdx.x * 64;
    const int d0 = blockIdx.y * 64;
    const int tid = threadIdx.x;           // 256
    const int c  = tid & 63;
    const int r4 = tid >> 6;
    #pragma unroll
    for (int i = 0; i < 16; ++i) {
        int row = r4 + i * 4;
        tile[row][c] = QKV[(size_t)(b * T_SEQ + t0 + row) * 3072 + 2048 + d0 + c];
    }
    __syncthreads();
    #pragma unroll
    for (int i = 0; i < 16; ++i) {
        int drow = r4 + i * 4;
        vT[((size_t)b * EMB + d0 + drow) * T_SEQ + t0 + c] = tile[c][drow];
    }
}

// ---------------------------------------------------------------- PV split-K
// 768 blocks = 8 XCD-groups x 96. xcd -> (bz = xcd>>1, half = xcd&1).
// idx = bid>>3: p = idx>>3 (0..11), ct = idx&7.
// half0: p<8  -> direct rt=p, full K, scaled -> d_out  (vT t<1024 only)
//        p>=8 -> part0 rt=p (8..11), K tiles [0,8)     -> d_out unscaled
// half1: p<4  -> part0 rt=12+p, K tiles [0,8)          -> d_out unscaled
//        p>=4 -> part1 rt=8+(p-4)=4+p, K [1024,(rt+1)*128) -> tmp1
// Both halves: 68 K-tiles of work. pv_finish combines rows >= 1024.
__global__ __launch_bounds__(256) void pv_split(
    const __hip_bfloat16* __restrict__ P,
    const __hip_bfloat16* __restrict__ Vt,
    float* __restrict__ out,
    float* __restrict__ tmp1,
    const float* __restrict__ Lbuf)
{
    const int bid  = blockIdx.x;             // 0..767
    const int xcd  = bid & 7;
    const int bz   = xcd >> 1;
    const int half = xcd & 1;
    const int idx  = bid >> 3;               // 0..95
    const int p    = idx >> 3;               // 0..11
    const int ct   = idx & 7;

    int rt, k0s, k0e;
    bool scaled = false;
    float* dst;
    if (half == 0) {
        if (p < 8) {
            rt = p; k0s = 0; k0e = (rt + 1) * 128; scaled = true;
            dst = out + (long)bz * 2097152 + (long)rt * 128 * 1024;
        } else {
            rt = p;  // 8..11
            k0s = 0; k0e = 1024;
            dst = out + (long)bz * 2097152 + (long)rt * 128 * 1024;
        }
    } else {
        if (p < 4) {
            rt = 12 + p; k0s = 0; k0e = 1024;
            dst = out + (long)bz * 2097152 + (long)rt * 128 * 1024;
        } else {
            rt = 4 + p;  // 8..15
            k0s = 1024; k0e = (rt + 1) * 128;
            dst = tmp1 + ((long)bz * 1024 + (long)(rt - 8) * 128) * 1024;
        }
    }

    __shared__ short lsA[2][128 * 32];
    __shared__ short lsB[2][128 * 32];

    const int tid  = threadIdx.x;
    const int wave = tid >> 6;
    const int lane = tid & 63;
    const int wr   = (wave >> 1) * 64;
    const int wc   = (wave &  1) * 64;
    const int srow = wave * 32 + (lane >> 2);
    const int scol = (lane & 3) * 8;
    const int frow = lane & 15;
    const int fk   = (lane >> 4) * 8;

    const short* A = (const short*)P  + (long)bz * 4194304 + (long)rt * 128 * 2048;
    const short* B = (const short*)Vt + (long)bz * 2097152 + (long)ct * 128 * 2048;

    f32x4 acc[4][4] = {};

    for (int k0 = k0s; k0 < k0e; k0 += 64) {
        const short* ga = A + (long)srow * 2048 + k0 + scol;
        const short* gb = B + (long)srow * 2048 + k0 + scol;
        load_lds16(ga,                   &lsA[0][(wave * 32) * 32]);
        load_lds16(ga + 16L * 2048,      &lsA[0][(wave * 32 + 16) * 32]);
        load_lds16(ga + 32,              &lsA[1][(wave * 32) * 32]);
        load_lds16(ga + 16L * 2048 + 32, &lsA[1][(wave * 32 + 16) * 32]);
        load_lds16(gb,                   &lsB[0][(wave * 32) * 32]);
        load_lds16(gb + 16L * 2048,      &lsB[0][(wave * 32 + 16) * 32]);
        load_lds16(gb + 32,              &lsB[1][(wave * 32) * 32]);
        load_lds16(gb + 16L * 2048 + 32, &lsB[1][(wave * 32 + 16) * 32]);
        __syncthreads();

        #pragma unroll
        for (int sub = 0; sub < 2; ++sub) {
            bf16x8 af[4], bfr[4];
            #pragma unroll
            for (int m = 0; m < 4; ++m)
                af[m] = *(const bf16x8*)&lsA[sub][(wr + m * 16 + frow) * 32 + fk];
            #pragma unroll
            for (int n = 0; n < 4; ++n)
                bfr[n] = *(const bf16x8*)&lsB[sub][(wc + n * 16 + frow) * 32 + fk];
            #pragma unroll
            for (int m = 0; m < 4; ++m)
                #pragma unroll
                for (int n = 0; n < 4; ++n)
                    acc[m][n] = __builtin_amdgcn_mfma_f32_16x16x32_bf16(
                        af[m], bfr[n], acc[m][n], 0, 0, 0);
        }
        __syncthreads();
    }

    const int orow = (lane >> 4) * 4;
    const int ocol = lane & 15;
    if (scaled) {
        const float* il = Lbuf + bz * T_SEQ + (long)rt * 128;
        #pragma unroll
        for (int m = 0; m < 4; ++m)
            #pragma unroll
            for (int r = 0; r < 4; ++r) {
                const long lrow = wr + m * 16 + orow + r;
                const float s = 1.f / il[lrow];
                #pragma unroll
                for (int n = 0; n < 4; ++n)
                    dst[lrow * 1024 + ct * 128 + wc + n * 16 + ocol] =
                        acc[m][n][r] * s;
            }
    } else {
        #pragma unroll
        for (int m = 0; m < 4; ++m)
            #pragma unroll
            for (int r = 0; r < 4; ++r) {
                const long lrow = wr + m * 16 + orow + r;
                #pragma unroll
                for (int n = 0; n < 4; ++n)
                    dst[lrow * 1024 + ct * 128 + wc + n * 16 + ocol] = acc[m][n][r];
            }
    }
}

// ---------------------------------------------------------------- PV finish
// rows >= 1024 per batch: out = (out + tmp1) / l.
__global__ void pv_finish(float* __restrict__ out,
                          const float* __restrict__ tmp1,
                          const float* __restrict__ Lbuf) {
    const int g = blockIdx.x;                // 0..4095
    const int b = g >> 10;
    const int r = (g & 1023) + 1024;
    const int c = threadIdx.x * 4;
    const float s = 1.f / Lbuf[b * T_SEQ + r];
    float* po = out + (long)b * 2097152 + (long)r * 1024 + c;
    float4 o = *(const float4*)po;
    float4 t = *(const float4*)&tmp1[((long)b * 1024 + (r - 1024)) * 1024 + c];
    o.x = (o.x + t.x) * s; o.y = (o.y + t.y) * s;
    o.z = (o.z + t.z) * s; o.w = (o.w + t.w) * s;
    *(float4*)po = o;
}

// ---------------------------------------------------------------- launch
extern "C" void kernel_launch(void* const* d_in, const int* in_sizes, int n_in,
                              void* d_out, int out_size, void* d_ws, size_t ws_size,
                              hipStream_t stream) {
    const float* x  = (const float*)d_in[0];
    const float* Wq = (const float*)d_in[1];
    const float* Wk = (const float*)d_in[2];
    const float* Wv = (const float*)d_in[3];

    char* ws = (char*)d_ws;
    // workspace (bytes):
    //   xb   @ 0         : 16,777,216   (dead after QKV; tmp1 aliases)
    //   wb   @ 16777216  :  6,291,456
    //   qkv  @ 23068672  : 50,331,648   (Q|K|V cols)
    //   vT   @ 73400320  : 16,777,216
    //   P    @ 90177536  : 33,554,432
    //   l    @ 123731968 :     32,768
    __hip_bfloat16* xb   = (__hip_bfloat16*)(ws);
    __hip_bfloat16* wb   = (__hip_bfloat16*)(ws + 16777216);
    __hip_bfloat16* qkv  = (__hip_bfloat16*)(ws + 23068672);
    __hip_bfloat16* vT   = (__hip_bfloat16*)(ws + 73400320);
    __hip_bfloat16* P    = (__hip_bfloat16*)(ws + 90177536);
    float*          Lbuf = (float*)        (ws + 123731968);
    float*          tmp1 = (float*)        (ws);              // aliases xb

    // 1) casts + Lbuf zero
    cast_all<<<dim3(11296), 256, 0, stream>>>(x, Wq, Wk, Wv, xb, wb, Lbuf);

    // 2) fused QKV -> qkv [8192][3072], XCD slab swizzle
    gemm_bt<1, 1><<<dim3(1536), 256, 0, stream>>>(
        xb, wb, qkv, nullptr,
        /*K*/1024, /*lda*/1024, /*ldb*/1024, /*ldc*/3072,
        0L, 0L, 0L);

    // 3) V^T per batch
    transpose_v<<<dim3(32, 16, 4), 256, 0, stream>>>(qkv, vT);

    // 4) P = exp(mask(QK^T)/32) bf16 + atomic rowsums, XCD-grouped triangle
    gemm_bt<3, 3><<<dim3(544), 256, 0, stream>>>(
        qkv, qkv + 1024, P, Lbuf,
        /*K*/1024, /*lda*/3072, /*ldb*/3072, /*ldc*/2048,
        /*bA*/6291456L, /*bB*/6291456L, /*bC*/4194304L);

    // 5) O = P @ V ; XCD-grouped split-K, direct rows scaled in-epilogue
    pv_split<<<dim3(768), 256, 0, stream>>>(
        P, vT, (float*)d_out, tmp1, Lbuf);

    // 6) combine + scale split rows
    pv_finish<<<dim3(4096), 256, 0, stream>>>((float*)d_out, tmp1, Lbuf);
}